// Round 17
// baseline (1397.789 us; speedup 1.0000x reference)
//
#include <hip/hip_runtime.h>

// Multi-layer tanh RNN, layer-pipelined persistent kernel.
// R17 = R16 (best, 1371us) + two proven-safe cuts:
//  - single-plane RTN-bf16 weights (R14/R15 measured absmax 2.38e-3 vs
//    9.8e-3 threshold): MFMA 16 -> 8 per step, acc chains 8 -> 4 deep,
//    Bf 128 -> 64 VGPRs.
//  - K=8 / RD=16: eff-steps 656 -> 584 (fill 144 -> 72 steps, ~-150us);
//    flag-boundary overhead measured small at K=16, 2x events acceptable.
// Carried: bf16 LDS state (A = direct ds_read_b128, zero conversion),
// fp32 ring, 4-wave column-split, 1 lds_barrier/step, deferred stores,
// agent-scope flags, NB=32/BC=16, 2 blk/CU.

#define HH   100   // hidden
#define HS   132   // padded fp32 stride (bias etc.)
#define HSS  136   // bf16 LDS row stride in shorts (272B, b128-aligned)
#define NL   10    // layers
#define BBS  512   // batch
#define TTS  512   // time
#define NB   32    // batch chunks
#define BC   16    // batch per chunk
#define NT   256   // threads per block

typedef __attribute__((ext_vector_type(8))) short short8;
typedef __attribute__((ext_vector_type(4))) float f32x4;
typedef __attribute__((ext_vector_type(2))) unsigned int u32x2;

__global__ void init_ws_kernel(int* wsi) {
  int i = blockIdx.x * blockDim.x + threadIdx.x;
  if (i < 16384) wsi[i] = 0;   // zero both flag regions (64KB)
}

__device__ __forceinline__ int flag_idx(int iface, int chunk) {
  return (iface * NB + chunk) * 16;
}

__device__ __forceinline__ void lds_barrier() {
  __asm__ __volatile__("s_waitcnt lgkmcnt(0)\n\ts_barrier" ::: "memory");
}
__device__ __forceinline__ void ctl_barrier() {
  __asm__ __volatile__("s_barrier" ::: "memory");
}

__device__ __forceinline__ float fast_tanh(float v) {
  float e = __expf(2.0f * v);
  return 1.0f - 2.0f * __builtin_amdgcn_rcpf(e + 1.0f);
}

__device__ __forceinline__ unsigned short bf_rtn(float x) {
  return (unsigned short)((__float_as_uint(x) + 0x8000u) >> 16);
}
__device__ __forceinline__ unsigned pack_rtn(float x0, float x1) {
  unsigned u0 = __float_as_uint(x0) + 0x8000u;
  unsigned u1 = __float_as_uint(x1) + 0x8000u;
  return (u0 >> 16) | (u1 & 0xFFFF0000u);
}
// f32x4 -> 4 bf16 packed in 8 bytes
__device__ __forceinline__ u32x2 pack4(f32x4 q) {
  u32x2 d;
  d[0] = pack_rtn(q[0], q[1]);
  d[1] = pack_rtn(q[2], q[3]);
  return d;
}
// 8 fp32 -> short8 RTN bf16
__device__ __forceinline__ short8 build1(f32x4 lo, f32x4 hi) {
  __attribute__((ext_vector_type(4))) unsigned int w;
  w[0] = pack_rtn(lo[0], lo[1]);
  w[1] = pack_rtn(lo[2], lo[3]);
  w[2] = pack_rtn(hi[0], hi[1]);
  w[3] = pack_rtn(hi[2], hi[3]);
  return __builtin_bit_cast(short8, w);
}

__global__ __launch_bounds__(NT, 2) void rnn_pipe(
    const float* __restrict__ x,     // [B,T,1]
    const float* __restrict__ h0,    // [L,B,H]
    const float* __restrict__ Wih0,  // [H,1]
    const float* __restrict__ Wih,   // [L-1,H,H]
    const float* __restrict__ Whh,   // [L,H,H]
    const float* __restrict__ bih,   // [L,H]
    const float* __restrict__ bhh,   // [L,H]
    const float* __restrict__ Wout,  // [1,H]
    const float* __restrict__ bout,  // [1]
    float* __restrict__ out,         // [B*T] outs ++ [L*B*H] h_final
    float* __restrict__ ring,
    int*   __restrict__ wsi,
    int Kv, int RDv)
{
  const int layer = blockIdx.x / NB;
  const int chunk = blockIdx.x % NB;
  const int tid   = threadIdx.x;
  const int Km = Kv - 1, RDm = RDv - 1;
  const int NE = BC * HH;  // 1600 elements per activation slot

  const int wave = tid >> 6, lane = tid & 63;
  const int quad = lane >> 4, lp = lane & 15;

  __shared__ unsigned short hbuf[2][BC][HSS];  // recurrent state bf16
  __shared__ unsigned short ibuf[2][BC][HSS];  // staged prev-layer input bf16
  __shared__ float bias[HS];
  __shared__ float wi0s[HS];
  __shared__ float wouts[HS];
  __shared__ float xin[2][BC];

  // ---- one-time LDS init ----
  for (int i = tid; i < 2 * BC * HSS; i += NT) {
    (&hbuf[0][0][0])[i] = 0; (&ibuf[0][0][0])[i] = 0;
  }
  for (int i = tid; i < HS; i += NT) {
    bias[i]  = (i < HH) ? (bih[layer * HH + i] + bhh[layer * HH + i]) : 0.f;
    wi0s[i]  = (i < HH) ? Wih0[i] : 0.f;
    wouts[i] = (i < HH) ? Wout[i] : 0.f;
  }
  if (tid < BC) { xin[0][tid] = 0.f; xin[1][tid] = 0.f; }
  __syncthreads();
  for (int idx = tid; idx < NE; idx += NT)
    hbuf[0][idx / HH][idx % HH] =
        bf_rtn(h0[((size_t)layer * BBS + chunk * BC + idx / HH) * HH + idx % HH]);
  __syncthreads();

  // ---- B-fragments: fused W = [Whh (k 0..99) ; Wih (k 128..227)],
  // single-plane RTN bf16 (R14-proven numerics): 64 VGPRs.
  short8 Bf[8][2];
  #pragma unroll
  for (int kc = 0; kc < 8; ++kc) {
    #pragma unroll
    for (int ntl = 0; ntl < 2; ++ntl) {
      const int n = wave * 32 + ntl * 16 + lp;
      f32x4 wlo = {}, whi = {};
      #pragma unroll
      for (int j = 0; j < 8; ++j) {
        const int k = kc * 32 + quad * 8 + j;
        float w = 0.f;
        if (kc < 4) {
          if (k < HH && n < HH) w = Whh[(size_t)layer * HH * HH + n * HH + k];
        } else {
          const int kk = k - 128;
          if (layer > 0 && kk >= 0 && kk < HH && n < HH)
            w = Wih[(size_t)(layer - 1) * HH * HH + n * HH + kk];
        }
        if (j < 4) wlo[j] = w; else whi[j - 4] = w;
      }
      Bf[kc][ntl] = build1(wlo, whi);
    }
  }

  // ---- flags / ring pointers (R8-proven protocol, agent scope) ----
  int* prog_in  = (layer > 0)      ? wsi + flag_idx(layer - 1, chunk)        : nullptr;
  int* cons_in  = (layer > 0)      ? wsi + 8192 + flag_idx(layer - 1, chunk) : nullptr;
  int* prog_out = (layer < NL - 1) ? wsi + flag_idx(layer, chunk)            : nullptr;
  int* cons_out = (layer < NL - 1) ? wsi + 8192 + flag_idx(layer, chunk)     : nullptr;
  const size_t slot_sz = (size_t)NE;  // 1600 floats
  float* ring_in  = (layer > 0)      ? ring + (size_t)((layer - 1) * NB + chunk) * RDv * slot_sz : nullptr;
  float* ring_out = (layer < NL - 1) ? ring + (size_t)(layer * NB + chunk) * RDv * slot_sz       : nullptr;

  const int jcv[2] = { wave * 32 + lp, wave * 32 + 16 + lp };   // C columns
  const float br[2]  = { bias[jcv[0]], bias[jcv[1]] };
  const float w0r[2] = { wi0s[jcv[0]], wi0s[jcv[1]] };
  const float boutv = bout[0];

  f32x4 hreg[2];             // step-t h values fp32 (deferred ring stores)
  float dso = 0.f;           // deferred layer-9 output
  float px = 0.f;
  bool have_ring_def = false, have_out_def = false;

  for (int t = 0; t < TTS; ++t) {
    const int par = t & 1, nxt = par ^ 1;
    const bool batch_start = (t & Km) == 0;
    const bool batch_last  = (t & Km) == Km;

    // ---- batch boundary: wait + exposed staging of slot t into parity par ----
    if (batch_start) {
      if (tid == 0) {
        if (layer > 0) {
          while (__hip_atomic_load(prog_in, __ATOMIC_RELAXED, __HIP_MEMORY_SCOPE_AGENT) < t + Kv)
            __builtin_amdgcn_s_sleep(1);
          (void)__hip_atomic_load(prog_in, __ATOMIC_ACQUIRE, __HIP_MEMORY_SCOPE_AGENT);
        }
        if (layer < NL - 1 && t + Kv > RDv) {
          while (__hip_atomic_load(cons_out, __ATOMIC_RELAXED, __HIP_MEMORY_SCOPE_AGENT) < t + Kv - RDv)
            __builtin_amdgcn_s_sleep(1);
        }
      }
      ctl_barrier();
      if (layer > 0) {
        const float* src = ring_in + (size_t)(t & RDm) * slot_sz;
        int i0 = tid * 4;
        if (i0 < NE) {
          u32x2 d = pack4(*(const f32x4*)(src + i0));
          *(u32x2*)&ibuf[par][i0 / HH][i0 % HH] = d;
        }
        int i1 = i0 + 1024;
        if (i1 < NE) {
          u32x2 d = pack4(*(const f32x4*)(src + i1));
          *(u32x2*)&ibuf[par][i1 / HH][i1 % HH] = d;
        }
      } else if (t == 0) {
        if (tid < BC) xin[0][tid] = x[(size_t)(chunk * BC + tid) * TTS];
      }
      lds_barrier();
    }

    // ---- issue deferred stores from step t-1 (stay in flight past barrier) ----
    if (have_ring_def) {
      float* dst = ring_out + (size_t)((t - 1) & RDm) * slot_sz;
      #pragma unroll
      for (int ntl = 0; ntl < 2; ++ntl)
        if (jcv[ntl] < HH)
          #pragma unroll
          for (int r = 0; r < 4; ++r)
            dst[(size_t)(quad * 4 + r) * HH + jcv[ntl]] = hreg[ntl][r];
      have_ring_def = false;
    }
    if (have_out_def) {
      if ((tid & 15) == 0)
        out[(size_t)(chunk * BC + (tid >> 4)) * TTS + (t - 1)] = dso;
      have_out_def = false;
    }

    // ---- prefetch inp_{t+1} into regs (staged into ibuf[nxt] post-compute) ----
    f32x4 p0 = {}, p1 = {};
    bool pre = false;
    if (layer > 0) {
      if (!batch_last && t + 1 < TTS) {
        const float* src = ring_in + (size_t)((t + 1) & RDm) * slot_sz;
        int i0 = tid * 4;
        if (i0 < NE) p0 = *(const f32x4*)(src + i0);
        if (i0 + 1024 < NE) p1 = *(const f32x4*)(src + i0 + 1024);
        pre = true;
      }
    } else {
      if (t + 1 < TTS && tid < BC) px = x[(size_t)(chunk * BC + tid) * TTS + (t + 1)];
    }

    // ---- MFMA: A = direct bf16 ds_read_b128, B single-plane -> 1 MFMA/kc ----
    f32x4 acc[2] = {}, acc2[2] = {};
    auto mfma_kc = [&](f32x4* accp, const unsigned short (*buf)[HSS], int koff, int bfi) {
      short8 A1 = *(const short8*)&buf[lp][koff + quad * 8];
      #pragma unroll
      for (int ntl = 0; ntl < 2; ++ntl)
        accp[ntl] = __builtin_amdgcn_mfma_f32_16x16x32_bf16(
            A1, Bf[bfi][ntl], accp[ntl], 0, 0, 0);
    };
    #pragma unroll
    for (int kc = 0; kc < 4; ++kc) mfma_kc(acc, hbuf[par], kc * 32, kc);
    if (layer > 0) {
      #pragma unroll
      for (int kc = 0; kc < 4; ++kc) mfma_kc(acc2, ibuf[par], kc * 32, kc + 4);
    }

    // ---- epilogue: merge, bias(+x*w0), tanh, pack bf16, write hbuf[nxt] ----
    #pragma unroll
    for (int ntl = 0; ntl < 2; ++ntl) {
      #pragma unroll
      for (int r = 0; r < 4; ++r) {
        const int m = quad * 4 + r;
        float v = acc[ntl][r] + acc2[ntl][r] + br[ntl];
        if (layer == 0) v += xin[par][m] * w0r[ntl];
        float h = fast_tanh(v);
        hreg[ntl][r] = h;
        if (jcv[ntl] < HH) hbuf[nxt][m][jcv[ntl]] = bf_rtn(h);
      }
    }

    // batch-last ring store cannot be deferred past the flag publish
    if (layer < NL - 1 && batch_last) {
      float* dst = ring_out + (size_t)(t & RDm) * slot_sz;
      #pragma unroll
      for (int ntl = 0; ntl < 2; ++ntl)
        if (jcv[ntl] < HH)
          #pragma unroll
          for (int r = 0; r < 4; ++r)
            dst[(size_t)(quad * 4 + r) * HH + jcv[ntl]] = hreg[ntl][r];
    }
    if (t == TTS - 1) {   // final hidden state, fp32-exact from registers
      #pragma unroll
      for (int ntl = 0; ntl < 2; ++ntl)
        if (jcv[ntl] < HH)
          #pragma unroll
          for (int r = 0; r < 4; ++r)
            out[(size_t)BBS * TTS +
                ((size_t)layer * BBS + chunk * BC + quad * 4 + r) * HH + jcv[ntl]] =
                hreg[ntl][r];
    }

    // ---- stage prefetched inp_{t+1} into ibuf[nxt] / xin[nxt] ----
    if (pre) {
      int i0 = tid * 4;
      if (i0 < NE) *(u32x2*)&ibuf[nxt][i0 / HH][i0 % HH] = pack4(p0);
      int i1 = i0 + 1024;
      if (i1 < NE) *(u32x2*)&ibuf[nxt][i1 / HH][i1 % HH] = pack4(p1);
    }
    if (layer == 0 && t + 1 < TTS && tid < BC) xin[nxt][tid] = px;

    if (batch_last) {
      __syncthreads();   // full drain: ALL waves' ring stores visible pre-flag
    } else {
      lds_barrier();     // LDS ordered; global stores remain in flight
    }

    // ---- flags (once per batch) ----
    if (batch_last && tid == 0) {
      if (layer < NL - 1)
        __hip_atomic_store(prog_out, t + 1, __ATOMIC_RELEASE, __HIP_MEMORY_SCOPE_AGENT);
      if (layer > 0)
        __hip_atomic_store(cons_in, t + 1, __ATOMIC_RELAXED, __HIP_MEMORY_SCOPE_AGENT);
    }

    // ---- layer-9 output dot (reads fresh hbuf[nxt], reconstruct bf16) ----
    if (layer == NL - 1) {
      const int b = tid >> 4, seg = tid & 15;
      float s = 0.f;
      #pragma unroll
      for (int jj = 0; jj < 7; ++jj) {
        const int j = seg * 7 + jj;
        if (j < HH) {
          float h = __uint_as_float((unsigned)hbuf[nxt][b][j] << 16);
          s += h * wouts[j];
        }
      }
      s += __shfl_xor(s, 1, 16);
      s += __shfl_xor(s, 2, 16);
      s += __shfl_xor(s, 4, 16);
      s += __shfl_xor(s, 8, 16);
      dso = s + boutv;
      if (t < TTS - 1) have_out_def = true;
    }
    if (layer < NL - 1 && !batch_last) have_ring_def = true;
  }

  // flush last layer-9 outputs (t = TTS-1)
  if (layer == NL - 1 && (tid & 15) == 0)
    out[(size_t)(chunk * BC + (tid >> 4)) * TTS + (TTS - 1)] = dso;
}

extern "C" void kernel_launch(void* const* d_in, const int* in_sizes, int n_in,
                              void* d_out, int out_size, void* d_ws, size_t ws_size,
                              hipStream_t stream) {
  const float* x    = (const float*)d_in[0];
  const float* h0   = (const float*)d_in[1];
  const float* Wih0 = (const float*)d_in[2];
  const float* Wih  = (const float*)d_in[3];
  const float* Whh  = (const float*)d_in[4];
  const float* bih  = (const float*)d_in[5];
  const float* bhh  = (const float*)d_in[6];
  const float* Wout = (const float*)d_in[7];
  const float* bout = (const float*)d_in[8];
  float* out = (float*)d_out;

  int*   wsi  = (int*)d_ws;
  float* ring = (float*)((char*)d_ws + 65536);

  // K=8 / RD=16 (fill 72 steps); fall back shallower if ws is tight.
  const size_t slot_bytes = (size_t)BC * HH * 4;   // 6400
  int RDv = 16;
  while (RDv > 2 && 65536 + (size_t)(NL - 1) * NB * RDv * slot_bytes > ws_size)
    RDv >>= 1;
  int Kv = RDv / 2;

  hipLaunchKernelGGL(init_ws_kernel, dim3(64), dim3(256), 0, stream, wsi);
  hipLaunchKernelGGL(rnn_pipe, dim3(NL * NB), dim3(NT), 0, stream,
                     x, h0, Wih0, Wih, Whh, bih, bhh, Wout, bout, out, ring, wsi,
                     Kv, RDv);
}